// Round 8
// baseline (175.947 us; speedup 1.0000x reference)
//
#include <hip/hip_runtime.h>
#include <stdint.h>

// Shapes (fixed for this problem)
#define B_   4
#define H_   16
#define S_   1024
#define D_   128
#define BM   128                 // Q rows per block (4 waves x 32 q-rows)
#define BN   32                  // K/V rows per iteration
#define NKT  (S_ / BN)           // 32
#define NTHREADS 256

typedef float f32x4 __attribute__((ext_vector_type(4)));
typedef short s16x8 __attribute__((ext_vector_type(8)));   // 8 bf16 (MFMA A/B frag)
typedef short s16x4 __attribute__((ext_vector_type(4)));
typedef int   i32x4 __attribute__((ext_vector_type(4)));

static __device__ __forceinline__ uint16_t f2bf(float f) {
  uint32_t u = __float_as_uint(f);
  u += 0x7FFFu + ((u >> 16) & 1u);          // round-to-nearest-even
  return (uint16_t)(u >> 16);
}
static __device__ __forceinline__ float bf2f(uint16_t h) {
  return __uint_as_float((uint32_t)h << 16);
}

static __device__ __forceinline__ void gl16(const void* g, void* l) {
  __builtin_amdgcn_global_load_lds(
      (const __attribute__((address_space(1))) unsigned int*)g,
      (__attribute__((address_space(3))) unsigned int*)l, 16, 0, 0);
}

// ws layout: [0,16M) Kbf tiles, [16M,32M) Vbf tiles, [32M,32.5M) mask bitwords.
// K tile (bh,kt): 8192B; chunk16B[(ks*2+nt)*64+lane] = K[kt*32+16nt+llo][32ks+8lhi..+7]
// V tile (bh,kt): 8192B; chunk16B[nt*64+lane]        = V^T[d=16nt+llo][kt*32+8lhi..+7]
// mask (word-major): wsM[(b*32 + w)*1024 + r] = bits of mask[b][r][32w..32w+31]
#define WSK_BYTES  16777216
#define WSV_BYTES  16777216
#define WSM_BYTES  524288
#define WS_NEED    (WSK_BYTES + WSV_BYTES + WSM_BYTES)

// ============================ pre-pass ====================================
__global__ __launch_bounds__(256)
void prepass_kernel(const float* __restrict__ k, const float* __restrict__ v,
                    const int* __restrict__ mask,
                    char* __restrict__ wsK, char* __restrict__ wsV,
                    uint32_t* __restrict__ wsM)
{
  int gid = blockIdx.x * 256 + threadIdx.x;
  if (gid < 1048576) {                       // ---- K chunks ----
    int tile = gid >> 9, c = gid & 511;
    int ks = c >> 7, nt = (c >> 6) & 1, lane = c & 63;
    int row = (tile & 31) * 32 + 16 * nt + (lane & 15);
    int col = 32 * ks + 8 * (lane >> 4);
    const float* src = k + ((size_t)(tile >> 5) * S_ + row) * D_ + col;
    f32x4 x0 = *(const f32x4*)src;
    f32x4 x1 = *(const f32x4*)(src + 4);
    s16x8 h;
    h[0]=f2bf(x0[0]); h[1]=f2bf(x0[1]); h[2]=f2bf(x0[2]); h[3]=f2bf(x0[3]);
    h[4]=f2bf(x1[0]); h[5]=f2bf(x1[1]); h[6]=f2bf(x1[2]); h[7]=f2bf(x1[3]);
    *(s16x8*)(wsK + (size_t)gid * 16) = h;
  } else if (gid < 2097152) {                // ---- V chunks (transposed) ----
    int gv = gid - 1048576;
    int tile = gv >> 9, c = gv & 511;
    int nt = c >> 6, lane = c & 63;
    int d   = 16 * nt + (lane & 15);
    int kv0 = (tile & 31) * 32 + 8 * (lane >> 4);
    const float* src = v + ((size_t)(tile >> 5) * S_ + kv0) * D_ + d;
    s16x8 h;
    #pragma unroll
    for (int i = 0; i < 8; ++i) h[i] = f2bf(src[(size_t)i * D_]);
    *(s16x8*)(wsV + (size_t)gv * 16) = h;
  } else if (gid < 2228224) {                // ---- mask bitwords (word-major) ----
    int gm = gid - 2097152;                  // 0..131071
    int gro = gm >> 5;                       // b*1024 + r
    int w   = gm & 31;
    const int* src = mask + (size_t)gro * S_ + w * 32;
    uint32_t bits = 0;
    #pragma unroll
    for (int i = 0; i < 32; ++i) bits |= (src[i] != 0 ? 1u : 0u) << i;
    wsM[((size_t)(gro >> 10) * 32 + w) * 1024 + (gro & 1023)] = bits;
  }
}

// ============================ main kernel =================================
// LDS map (40960 B):
//  [    0,16384) lK dbuf (8KB each), fragment-major
//  [16384,32768) lV dbuf (8KB each), fragment-major
//  [32768,40960) lS: per wave 2KB; chunk16B[qb*64 + lane] = S[16qb+llo][8lhi..+7]
// All MFMA-operand ds_read_b128 are base + lane*16 -> conflict-free.
__global__ __launch_bounds__(NTHREADS)
__attribute__((amdgpu_waves_per_eu(2)))    // <=256 VGPR: hold ~150 live regs, no squeeze
void attn_relu15_main(const float* __restrict__ q,
                      const char* __restrict__ wsK, const char* __restrict__ wsV,
                      const uint32_t* __restrict__ wsM,
                      float* __restrict__ outp, float* __restrict__ attnp)
{
  const int blk = blockIdx.x;                 // 512 blocks
  const int g   = (blk & 7) * 64 + (blk >> 3);  // XCD-grouped bijection
  const int bh  = g >> 3;                     // 0..63 (8 heads per XCD -> 4MB L2 set)
  const int qt  = g & 7;                      // 0..7
  const int b   = bh >> 4;

  const int tid  = threadIdx.x;
  const int lane = tid & 63;
  const int wq   = tid >> 6;                  // wave owns q-rows [32wq, 32wq+32)
  const int lhi  = lane >> 4;
  const int llo  = lane & 15;

  __shared__ __align__(16) char smem[40960];
  char* const lK0 = smem;
  char* const lV0 = smem + 16384;
  char* const lSw = smem + 32768 + wq * 2048;

  const float*    qg  = q + (size_t)bh * (S_ * D_) + (size_t)qt * BM * D_;
  const char*     kw  = wsK + (size_t)(bh * 32) * 8192;
  const char*     vw  = wsV + (size_t)(bh * 32) * 8192;
  const uint32_t* mwb = wsM + (size_t)b * 32768 + qt * BM + 32 * wq + 4 * lhi;
  float*          ag  = attnp + (size_t)bh * S_ * S_ + (size_t)qt * BM * S_;
  float*          og  = outp  + (size_t)bh * (S_ * D_) + (size_t)qt * BM * D_;

  const float invT = 0.08838834764831843f;    // 1/sqrt(128)

  // ---- Q fragments into registers (scaled, bf16), loaded once ----
  s16x8 qf[2][4];
  #pragma unroll
  for (int qb = 0; qb < 2; ++qb) {
    const float* qrow = qg + (size_t)(32 * wq + 16 * qb + llo) * D_;
    #pragma unroll
    for (int ks = 0; ks < 4; ++ks) {
      int d0 = 32 * ks + 8 * lhi;
      f32x4 x0 = *(const f32x4*)(qrow + d0);
      f32x4 x1 = *(const f32x4*)(qrow + d0 + 4);
      s16x8 h;
      h[0]=f2bf(x0[0]*invT); h[1]=f2bf(x0[1]*invT); h[2]=f2bf(x0[2]*invT); h[3]=f2bf(x0[3]*invT);
      h[4]=f2bf(x1[0]*invT); h[5]=f2bf(x1[1]*invT); h[6]=f2bf(x1[2]*invT); h[7]=f2bf(x1[3]*invT);
      qf[qb][ks] = h;
    }
  }

  // ---- prologue: DMA tile 0 into buffer 0 ----
  #pragma unroll
  for (int rep = 0; rep < 2; ++rep) {
    gl16(kw + rep * 4096 + tid * 16, lK0 + rep * 4096 + wq * 1024);
    gl16(vw + rep * 4096 + tid * 16, lV0 + rep * 4096 + wq * 1024);
  }
  asm volatile("s_waitcnt vmcnt(0) lgkmcnt(0)" ::: "memory");
  __builtin_amdgcn_s_barrier();
  __builtin_amdgcn_sched_barrier(0);

  f32x4 oacc[2][8];
  #pragma unroll
  for (int i = 0; i < 2; ++i)
    #pragma unroll
    for (int j = 0; j < 8; ++j) oacc[i][j] = (f32x4){0.f,0.f,0.f,0.f};

  int cur = 0;
  for (int kt = 0; kt < NKT; ++kt) {
    const bool pf = (kt + 1 < NKT);
    char* lKc = lK0 + cur * 8192;
    char* lVc = lV0 + cur * 8192;

    // ---- (1) mask bitwords: 2 x i32x4 (rows 16qb+4lhi..+3, word kt) ----
    i32x4 mv[2];
    #pragma unroll
    for (int qb = 0; qb < 2; ++qb)
      mv[qb] = *(const i32x4*)(mwb + (size_t)kt * 1024 + 16 * qb);

    // ---- (2) DMA next tile into other buffer (in flight all iteration) ----
    if (pf) {
      const char* kn = kw + (size_t)(kt + 1) * 8192;
      const char* vn = vw + (size_t)(kt + 1) * 8192;
      char* lKn = lK0 + (cur ^ 1) * 8192;
      char* lVn = lV0 + (cur ^ 1) * 8192;
      #pragma unroll
      for (int rep = 0; rep < 2; ++rep) {
        gl16(kn + rep * 4096 + tid * 16, lKn + rep * 4096 + wq * 1024);
        gl16(vn + rep * 4096 + tid * 16, lVn + rep * 4096 + wq * 1024);
      }
    }
    __builtin_amdgcn_sched_barrier(0);   // nothing below moves above the DMA

    // ---- (3) QK^T: 32 q-rows x 32 kv per wave ----
    f32x4 sacc[2][2];
    #pragma unroll
    for (int i = 0; i < 2; ++i) { sacc[i][0] = (f32x4){0,0,0,0}; sacc[i][1] = sacc[i][0]; }
    #pragma unroll
    for (int ks = 0; ks < 4; ++ks) {
      s16x8 bfr[2];
      #pragma unroll
      for (int nt = 0; nt < 2; ++nt)
        bfr[nt] = *(s16x8*)(lKc + (ks * 2 + nt) * 1024 + lane * 16);
      #pragma unroll
      for (int qb = 0; qb < 2; ++qb)
        #pragma unroll
        for (int nt = 0; nt < 2; ++nt)
          sacc[qb][nt] = __builtin_amdgcn_mfma_f32_16x16x32_bf16(
              qf[qb][ks], bfr[nt], sacc[qb][nt], 0, 0, 0);
    }

    // ---- (4) clip + mask -> lS (bf16, fragment-major) ----
    #pragma unroll
    for (int qb = 0; qb < 2; ++qb) {
      #pragma unroll
      for (int nt = 0; nt < 2; ++nt) {
        char* sb = lSw + qb * 1024 + (2 * nt + (llo >> 3)) * 256 + (llo & 7) * 2;
        #pragma unroll
        for (int j = 0; j < 4; ++j) {
          float val = fminf(fmaxf(sacc[qb][nt][j], 0.f), 15.f);
          if (!(((uint32_t)mv[qb][j] >> (16 * nt + llo)) & 1u)) val = 0.f;
          *(uint16_t*)(sb + (4 * lhi + j) * 16) = f2bf(val);
        }
      }
    }

    // ---- (5) PV A-frags (also the attn repack source) ----
    s16x8 pa[2];
    #pragma unroll
    for (int qb = 0; qb < 2; ++qb)
      pa[qb] = *(s16x8*)(lSw + qb * 1024 + lane * 16);

    // ---- (6) attn stores straight from pa: rows 32wq+16qb+llo, kv 8lhi..+7 ----
    #pragma unroll
    for (int qb = 0; qb < 2; ++qb) {
      float* dst = ag + (size_t)(32 * wq + 16 * qb + llo) * S_ + kt * BN + 8 * lhi;
      f32x4 a0, a1;
      #pragma unroll
      for (int i = 0; i < 4; ++i) {
        a0[i] = bf2f((uint16_t)pa[qb][i]);
        a1[i] = bf2f((uint16_t)pa[qb][4 + i]);
      }
      __builtin_nontemporal_store(a0, (f32x4*)dst);
      __builtin_nontemporal_store(a1, (f32x4*)(dst + 4));
    }

    // ---- (7) PV: O[32 x 128] += S @ V^T (single K=32 step) ----
    #pragma unroll
    for (int nt = 0; nt < 8; ++nt) {
      s16x8 vb = *(s16x8*)(lVc + nt * 1024 + lane * 16);
      #pragma unroll
      for (int qb = 0; qb < 2; ++qb)
        oacc[qb][nt] = __builtin_amdgcn_mfma_f32_16x16x32_bf16(
            pa[qb], vb, oacc[qb][nt], 0, 0, 0);
    }

    // ---- (8) barrier: DMA complete (all but newest 4 stores), stores fly on
    asm volatile("s_waitcnt vmcnt(4) lgkmcnt(0)" ::: "memory");
    __builtin_amdgcn_s_barrier();
    __builtin_amdgcn_sched_barrier(0);
    cur ^= 1;
  }

  // ---- epilogue: O store; nt-inner order so 64B segments merge into lines ----
  #pragma unroll
  for (int qb = 0; qb < 2; ++qb)
    #pragma unroll
    for (int j = 0; j < 4; ++j) {
      int m = 32 * wq + 16 * qb + 4 * lhi + j;
      #pragma unroll
      for (int nt = 0; nt < 8; ++nt)
        __builtin_nontemporal_store(oacc[qb][nt][j], og + (size_t)m * D_ + 16 * nt + llo);
    }
}

// ===================== fallback (r5 kernel, passing) ======================
#define LDS_BARRIER() do {                                   \
    asm volatile("s_waitcnt lgkmcnt(0)" ::: "memory");       \
    __builtin_amdgcn_s_barrier();                            \
    __builtin_amdgcn_sched_barrier(0);                       \
  } while (0)

__global__ __launch_bounds__(NTHREADS)
__attribute__((amdgpu_waves_per_eu(4, 4)))
void attn_relu15_fallback(const float* __restrict__ q, const float* __restrict__ k,
                          const float* __restrict__ v, const int* __restrict__ mask,
                          float* __restrict__ outp, float* __restrict__ attnp)
{
  const int blk = blockIdx.x;
  const int g   = (blk & 7) * 128 + (blk >> 3);
  const int bh  = g >> 4;
  const int qt  = g & 15;
  const int b   = bh >> 4;
  const int tid  = threadIdx.x;
  const int lane = tid & 63;
  const int wq   = tid >> 6;
  const int lhi  = lane >> 4;
  const int llo  = lane & 15;

  __shared__ __align__(16) char smem[36864];
  char* const lK0 = smem;
  char* const lV0 = smem + 16384;
  char* const lS  = smem + 32768 + wq * 1024;

  const float* qg = q + (size_t)bh * (S_ * D_) + (size_t)qt * 64 * D_;
  const float* kg = k + (size_t)bh * (S_ * D_);
  const float* vg = v + (size_t)bh * (S_ * D_);
  const int*   mg = mask  + (size_t)b * S_ * S_ + (size_t)qt * 64 * S_;
  float*       ag = attnp + (size_t)bh * S_ * S_ + (size_t)qt * 64 * S_;
  float*       og = outp  + (size_t)bh * (S_ * D_) + (size_t)qt * 64 * D_;
  const float invT = 0.08838834764831843f;

  #define K_O(rep)   ((tid + NTHREADS * (rep)) * 8)
  #define K_ROW(o)   ((((o) >> 10) & 1) * 16 + (((o) >> 4) & 15))
  #define K_COL(o)   (((o) >> 11) * 32 + (((o) >> 8) & 3) * 8 + (((o) >> 3) & 1) * 4)

  s16x8 qf[4];
  {
    const float* qrow = qg + (size_t)(16 * wq + llo) * D_;
    #pragma unroll
    for (int ks = 0; ks < 4; ++ks) {
      int d0 = 32 * ks + 8 * lhi;
      f32x4 x0 = *(const f32x4*)(qrow + d0);
      f32x4 x1 = *(const f32x4*)(qrow + d0 + 4);
      s16x8 h;
      h[0]=f2bf(x0[0]*invT); h[1]=f2bf(x0[1]*invT); h[2]=f2bf(x0[2]*invT); h[3]=f2bf(x0[3]*invT);
      h[4]=f2bf(x1[0]*invT); h[5]=f2bf(x1[1]*invT); h[6]=f2bf(x1[2]*invT); h[7]=f2bf(x1[3]*invT);
      qf[ks] = h;
    }
  }
  {
    #pragma unroll
    for (int rep = 0; rep < 4; ++rep) {
      int o = K_O(rep);
      f32x4 x = *(const f32x4*)(kg + K_ROW(o) * D_ + K_COL(o));
      s16x4 h; h[0]=f2bf(x[0]); h[1]=f2bf(x[1]); h[2]=f2bf(x[2]); h[3]=f2bf(x[3]);
      *(s16x4*)(lK0 + o) = h;
    }
    #pragma unroll
    for (int rep = 0; rep < 4; ++rep) {
      int bid = (tid >> 2) + 64 * rep;
      int kb = bid >> 5, db = bid & 31, l2 = lane & 3;
      f32x4 x = *(const f32x4*)(vg + (size_t)(kb * 4 + l2) * D_ + db * 4);
      float v0=x[0], v1=x[1], v2=x[2], v3=x[3], t;
      t=(l2&1)?v0:v1; t=__shfl_xor(t,1); if(l2&1)v0=t; else v1=t;
      t=(l2&1)?v2:v3; t=__shfl_xor(t,1); if(l2&1)v2=t; else v3=t;
      t=(l2&2)?v0:v2; t=__shfl_xor(t,2); if(l2&2)v0=t; else v2=t;
      t=(l2&2)?v1:v3; t=__shfl_xor(t,2); if(l2&2)v1=t; else v3=t;
      int dd = db * 4 + l2;
      s16x4 h; h[0]=f2bf(v0); h[1]=f2bf(v1); h[2]=f2bf(v2); h[3]=f2bf(v3);
      *(s16x4*)(lV0 + (dd >> 4) * 1024 + ((kb >> 1) & 3) * 256
                    + (dd & 15) * 16 + (kb & 1) * 8) = h;
    }
  }
  LDS_BARRIER();

  f32x4 oacc[8];
  #pragma unroll
  for (int i = 0; i < 8; ++i) oacc[i] = (f32x4){0.f,0.f,0.f,0.f};

  int cur = 0;
  for (int kt = 0; kt < NKT; ++kt) {
    const bool pf = (kt + 1 < NKT);
    char* lKc = lK0 + cur * 8192;
    char* lVc = lV0 + cur * 8192;
    f32x4 kst[4];
    const float* kgt = kg + (size_t)(kt + 1) * BN * D_;
    if (pf) {
      #pragma unroll
      for (int rep = 0; rep < 4; ++rep) {
        int o = K_O(rep);
        kst[rep] = *(const f32x4*)(kgt + K_ROW(o) * D_ + K_COL(o));
      }
    }
    int mreg[8];
    #pragma unroll
    for (int nt = 0; nt < 2; ++nt)
      #pragma unroll
      for (int j = 0; j < 4; ++j)
        mreg[nt * 4 + j] =
          mg[(size_t)(16 * wq + 4 * lhi + j) * S_ + kt * BN + 16 * nt + llo];

    f32x4 sacc[2];
    sacc[0] = (f32x4){0.f,0.f,0.f,0.f}; sacc[1] = sacc[0];
    #pragma unroll
    for (int ks = 0; ks < 4; ++ks) {
      s16x8 bfr[2];
      #pragma unroll
      for (int nt = 0; nt < 2; ++nt)
        bfr[nt] = *(s16x8*)(lKc + (ks * 2 + nt) * 1024 + lane * 16);
      #pragma unroll
      for (int nt = 0; nt < 2; ++nt)
        sacc[nt] = __builtin_amdgcn_mfma_f32_16x16x32_bf16(qf[ks], bfr[nt], sacc[nt], 0, 0, 0);
    }

    f32x4 vst[4];
    const float* vgt = vg + (size_t)(kt + 1) * BN * D_;
    if (pf) {
      char* lKn = lK0 + (cur ^ 1) * 8192;
      #pragma unroll
      for (int rep = 0; rep < 4; ++rep) {
        f32x4 x = kst[rep];
        s16x4 h; h[0]=f2bf(x[0]); h[1]=f2bf(x[1]); h[2]=f2bf(x[2]); h[3]=f2bf(x[3]);
        *(s16x4*)(lKn + K_O(rep)) = h;
      }
      #pragma unroll
      for (int rep = 0; rep < 4; ++rep) {
        int bid = (tid >> 2) + 64 * rep;
        int kb = bid >> 5, db = bid & 31, l2 = lane & 3;
        vst[rep] = *(const f32x4*)(vgt + (size_t)(kb * 4 + l2) * D_ + db * 4);
      }
    }

    #pragma unroll
    for (int nt = 0; nt < 2; ++nt) {
      char* sb = lS + (2 * nt + (llo >> 3)) * 256 + (llo & 7) * 2;
      #pragma unroll
      for (int j = 0; j < 4; ++j) {
        float val = fminf(fmaxf(sacc[nt][j], 0.f), 15.f);
        if (mreg[nt * 4 + j] == 0) val = 0.f;
        *(uint16_t*)(sb + (4 * lhi + j) * 16) = f2bf(val);
      }
    }
    {
      s16x8 saf = *(s16x8*)(lS + lane * 16);
      #pragma unroll
      for (int nt = 0; nt < 8; ++nt) {
        s16x8 vb = *(s16x8*)(lVc + nt * 1024 + lane * 16);
        oacc[nt] = __builtin_amdgcn_mfma_f32_16x16x32_bf16(saf, vb, oacc[nt], 0, 0, 0);
      }
    }
    #pragma unroll
    for (int p = 0; p < 2; ++p) {
      int r  = 16 * wq + p * 8 + (lane >> 3);
      int cb = lane & 7;
      s16x4 sv = *(s16x4*)(lS + (cb >> 1) * 256 + ((r & 15) * 16) + (cb & 1) * 8);
      f32x4 a;
      a[0]=bf2f((uint16_t)sv[0]); a[1]=bf2f((uint16_t)sv[1]);
      a[2]=bf2f((uint16_t)sv[2]); a[3]=bf2f((uint16_t)sv[3]);
      __builtin_nontemporal_store(a, (f32x4*)(ag + (size_t)r * S_ + kt * BN + cb * 4));
    }
    if (pf) {
      char* lVn = lV0 + (cur ^ 1) * 8192;
      #pragma unroll
      for (int rep = 0; rep < 4; ++rep) {
        int bid = (tid >> 2) + 64 * rep;
        int kb = bid >> 5, db = bid & 31, l2 = lane & 3;
        f32x4 x = vst[rep];
        float v0=x[0], v1=x[1], v2=x[2], v3=x[3], t;
        t=(l2&1)?v0:v1; t=__shfl_xor(t,1); if(l2&1)v0=t; else v1=t;
        t=(l2&1)?v2:v3; t=__shfl_xor(t,1); if(l2&1)v2=t; else v3=t;
        t=(l2&2)?v0:v2; t=__shfl_xor(t,2); if(l2&2)v0=t; else v2=t;
        t=(l2&2)?v1:v3; t=__shfl_xor(t,2); if(l2&2)v1=t; else v3=t;
        int dd = db * 4 + l2;
        s16x4 h; h[0]=f2bf(v0); h[1]=f2bf(v1); h[2]=f2bf(v2); h[3]=f2bf(v3);
        *(s16x4*)(lVn + (dd >> 4) * 1024 + ((kb >> 1) & 3) * 256
                      + (dd & 15) * 16 + (kb & 1) * 8) = h;
      }
    }
    LDS_BARRIER();
    cur ^= 1;
  }
  #pragma unroll
  for (int nt = 0; nt < 8; ++nt) {
    int n = 16 * nt + llo;
    #pragma unroll
    for (int j = 0; j < 4; ++j) {
      int m = 16 * wq + 4 * lhi + j;
      __builtin_nontemporal_store(oacc[nt][j], og + (size_t)m * D_ + n);
    }
  }
}

extern "C" void kernel_launch(void* const* d_in, const int* in_sizes, int n_in,
                              void* d_out, int out_size, void* d_ws, size_t ws_size,
                              hipStream_t stream) {
  const float* q    = (const float*)d_in[0];
  const float* k    = (const float*)d_in[1];
  const float* v    = (const float*)d_in[2];
  const int*   mask = (const int*)d_in[3];
  float* outp  = (float*)d_out;
  float* attnp = outp + (size_t)B_ * H_ * S_ * D_;   // tuple: (out, attn) concat

  if (ws_size >= (size_t)WS_NEED && d_ws != nullptr) {
    char*     wsK = (char*)d_ws;
    char*     wsV = wsK + WSK_BYTES;
    uint32_t* wsM = (uint32_t*)(wsK + WSK_BYTES + WSV_BYTES);
    prepass_kernel<<<8704, 256, 0, stream>>>(k, v, mask, wsK, wsV, wsM);
    attn_relu15_main<<<dim3(B_ * H_ * (S_ / BM)), NTHREADS, 0, stream>>>(
        q, wsK, wsV, wsM, outp, attnp);
  } else {
    attn_relu15_fallback<<<dim3(B_ * H_ * (S_ / 64)), NTHREADS, 0, stream>>>(
        q, k, v, mask, outp, attnp);
  }
}

// Round 9
// 104.563 us; speedup vs baseline: 1.6827x; 1.6827x over previous
//
#include <hip/hip_runtime.h>
#include <stdint.h>

// Shapes (fixed for this problem)
#define B_   4
#define H_   16
#define S_   1024
#define D_   128
#define BM   64                  // Q rows per block (4 waves x 16 q-rows)
#define BN   32                  // K/V rows per iteration
#define NKT  (S_ / BN)           // 32
#define NTHREADS 256

typedef float f32x4 __attribute__((ext_vector_type(4)));
typedef short s16x8 __attribute__((ext_vector_type(8)));   // 8 bf16 (MFMA A/B frag)
typedef short s16x4 __attribute__((ext_vector_type(4)));

static __device__ __forceinline__ uint16_t f2bf(float f) {
  uint32_t u = __float_as_uint(f);
  u += 0x7FFFu + ((u >> 16) & 1u);          // round-to-nearest-even
  return (uint16_t)(u >> 16);
}
static __device__ __forceinline__ float bf2f(uint16_t h) {
  return __uint_as_float((uint32_t)h << 16);
}

static __device__ __forceinline__ void gl16(const void* g, void* l) {
  __builtin_amdgcn_global_load_lds(
      (const __attribute__((address_space(1))) unsigned int*)g,
      (__attribute__((address_space(3))) unsigned int*)l, 16, 0, 0);
}

// ws layout: [0,16M) Kbf tiles, [16M,32M) Vbf tiles, [32M,32.5M) mask bitwords.
// K tile (bh,kt): 8192B; chunk16B[(ks*2+nt)*64+lane] = K[kt*32+16nt+llo][32ks+8lhi..+7]
// V tile (bh,kt): 8192B; chunk16B[nt*64+lane][p]     = V[kt*32 + kv(8lhi+p)][d=16nt+llo]
//   with kv(s) = 16*((s&7)>>2) + 4*(s>>3) + (s&3)  (matches swapped-QK S layout)
// mask (word-major): wsM[(b*32 + w)*1024 + r] = bits of mask[b][r][32w..32w+31]
#define WSK_BYTES  16777216
#define WSV_BYTES  16777216
#define WSM_BYTES  524288
#define WS_NEED    (WSK_BYTES + WSV_BYTES + WSM_BYTES)

// ============================ pre-pass ====================================
__global__ __launch_bounds__(256)
void prepass_kernel(const float* __restrict__ k, const float* __restrict__ v,
                    const int* __restrict__ mask,
                    char* __restrict__ wsK, char* __restrict__ wsV,
                    uint32_t* __restrict__ wsM)
{
  int gid = blockIdx.x * 256 + threadIdx.x;
  if (gid < 1048576) {                       // ---- K chunks ----
    int tile = gid >> 9, c = gid & 511;
    int ks = c >> 7, nt = (c >> 6) & 1, lane = c & 63;
    int row = (tile & 31) * 32 + 16 * nt + (lane & 15);
    int col = 32 * ks + 8 * (lane >> 4);
    const float* src = k + ((size_t)(tile >> 5) * S_ + row) * D_ + col;
    f32x4 x0 = *(const f32x4*)src;
    f32x4 x1 = *(const f32x4*)(src + 4);
    s16x8 h;
    h[0]=f2bf(x0[0]); h[1]=f2bf(x0[1]); h[2]=f2bf(x0[2]); h[3]=f2bf(x0[3]);
    h[4]=f2bf(x1[0]); h[5]=f2bf(x1[1]); h[6]=f2bf(x1[2]); h[7]=f2bf(x1[3]);
    *(s16x8*)(wsK + (size_t)gid * 16) = h;
  } else if (gid < 2097152) {                // ---- V chunks (transposed, kv-permuted) ----
    int gv = gid - 1048576;
    int tile = gv >> 9, c = gv & 511;
    int nt = c >> 6, lane = c & 63;          // nt 0..7
    int llo = lane & 15, lhi = lane >> 4;
    int d   = 16 * nt + llo;
    const float* src = v + ((size_t)(tile >> 5) * S_ + (tile & 31) * 32 + 4 * lhi) * D_ + d;
    s16x8 h;
    #pragma unroll
    for (int p = 0; p < 8; ++p)              // kv = 16*(p>>2) + 4*lhi + (p&3)
      h[p] = f2bf(src[(size_t)((p & 3) + 16 * (p >> 2)) * D_]);
    *(s16x8*)(wsV + (size_t)gv * 16) = h;
  } else if (gid < 2228224) {                // ---- mask bitwords (word-major) ----
    int gm = gid - 2097152;                  // 0..131071
    int gro = gm >> 5;                       // b*1024 + r
    int w   = gm & 31;
    const int* src = mask + (size_t)gro * S_ + w * 32;
    uint32_t bits = 0;
    #pragma unroll
    for (int i = 0; i < 32; ++i) bits |= (src[i] != 0 ? 1u : 0u) << i;
    wsM[((size_t)(gro >> 10) * 32 + w) * 1024 + (gro & 1023)] = bits;
  }
}

// ============================ main kernel =================================
// LDS map (37376 B -> 4 blocks/CU, 16 waves/CU):
//  [    0,16384) lK dbuf (8KB each), fragment-major
//  [16384,32768) lV dbuf (8KB each), fragment-major (kv-permuted)
//  [32768,37376) lS: per wave 1152B = 16 rows x 72B (odd stride: ~2-way banks)
//                row q, byte kv*2 within 64B payload; repack scratch only.
__global__ __launch_bounds__(NTHREADS)
__attribute__((amdgpu_waves_per_eu(4, 4)))
void attn_relu15_main(const float* __restrict__ q,
                      const char* __restrict__ wsK, const char* __restrict__ wsV,
                      const uint32_t* __restrict__ wsM,
                      float* __restrict__ outp, float* __restrict__ attnp)
{
  const int blk = blockIdx.x;                    // 1024 blocks
  const int g   = (blk & 7) * 128 + (blk >> 3);  // XCD-grouped bijection
  const int bh  = g >> 4;
  const int qt  = g & 15;
  const int b   = bh >> 4;

  const int tid  = threadIdx.x;
  const int lane = tid & 63;
  const int wq   = tid >> 6;                 // wave owns q-rows [16wq, 16wq+16)
  const int lhi  = lane >> 4;
  const int llo  = lane & 15;

  __shared__ __align__(16) char smem[37376];
  char* const lK0 = smem;
  char* const lV0 = smem + 16384;
  char* const lS  = smem + 32768 + wq * 1152;

  const float*    qg  = q + (size_t)bh * (S_ * D_) + (size_t)qt * BM * D_;
  const char*     kw  = wsK + (size_t)(bh * 32) * 8192;
  const char*     vw  = wsV + (size_t)(bh * 32) * 8192;
  const uint32_t* mwb = wsM + (size_t)b * 32768 + qt * BM + 16 * wq + llo;
  float*          ag  = attnp + (size_t)bh * S_ * S_ + (size_t)qt * BM * S_;
  float*          og  = outp  + (size_t)bh * (S_ * D_) + (size_t)qt * BM * D_;

  const float invT = 0.08838834764831843f;   // 1/sqrt(128)

  // ---- Q fragments into registers (scaled, bf16), loaded once ----
  s16x8 qf[4];
  {
    const float* qrow = qg + (size_t)(16 * wq + llo) * D_;
    #pragma unroll
    for (int ks = 0; ks < 4; ++ks) {
      int d0 = 32 * ks + 8 * lhi;
      f32x4 x0 = *(const f32x4*)(qrow + d0);
      f32x4 x1 = *(const f32x4*)(qrow + d0 + 4);
      s16x8 h;
      h[0]=f2bf(x0[0]*invT); h[1]=f2bf(x0[1]*invT); h[2]=f2bf(x0[2]*invT); h[3]=f2bf(x0[3]*invT);
      h[4]=f2bf(x1[0]*invT); h[5]=f2bf(x1[1]*invT); h[6]=f2bf(x1[2]*invT); h[7]=f2bf(x1[3]*invT);
      qf[ks] = h;
    }
  }

  // ---- prologue: DMA tile 0 into buffer 0 ----
  #pragma unroll
  for (int rep = 0; rep < 2; ++rep) {
    gl16(kw + rep * 4096 + tid * 16, lK0 + rep * 4096 + wq * 1024);
    gl16(vw + rep * 4096 + tid * 16, lV0 + rep * 4096 + wq * 1024);
  }
  asm volatile("s_waitcnt vmcnt(0) lgkmcnt(0)" ::: "memory");
  __builtin_amdgcn_s_barrier();
  __builtin_amdgcn_sched_barrier(0);

  f32x4 oacc[8];
  #pragma unroll
  for (int i = 0; i < 8; ++i) oacc[i] = (f32x4){0.f,0.f,0.f,0.f};

  int cur = 0;
  for (int kt = 0; kt < NKT; ++kt) {
    const bool pf = (kt + 1 < NKT);
    char* lKc = lK0 + cur * 8192;
    char* lVc = lV0 + cur * 8192;

    // ---- (1) mask bitword: ONE scalar load (row llo's word kt) ----
    uint32_t mword = mwb[(size_t)kt * 1024];
    __builtin_amdgcn_sched_barrier(0);

    // ---- (2) DMA next tile into other buffer (in flight all iteration) ----
    if (pf) {
      const char* kn = kw + (size_t)(kt + 1) * 8192;
      const char* vn = vw + (size_t)(kt + 1) * 8192;
      char* lKn = lK0 + (cur ^ 1) * 8192;
      char* lVn = lV0 + (cur ^ 1) * 8192;
      #pragma unroll
      for (int rep = 0; rep < 2; ++rep) {
        gl16(kn + rep * 4096 + tid * 16, lKn + rep * 4096 + wq * 1024);
        gl16(vn + rep * 4096 + tid * 16, lVn + rep * 4096 + wq * 1024);
      }
    }
    __builtin_amdgcn_sched_barrier(0);   // nothing below moves above the DMA

    // ---- (3) QK^T, SWAPPED operands: lane holds S[q=llo][kv=16nt+4lhi+j] ----
    f32x4 sacc[2];
    sacc[0] = (f32x4){0.f,0.f,0.f,0.f}; sacc[1] = sacc[0];
    #pragma unroll
    for (int ks = 0; ks < 4; ++ks) {
      s16x8 bfr[2];
      #pragma unroll
      for (int nt = 0; nt < 2; ++nt)
        bfr[nt] = *(s16x8*)(lKc + (ks * 2 + nt) * 1024 + lane * 16);
      #pragma unroll
      for (int nt = 0; nt < 2; ++nt)
        sacc[nt] = __builtin_amdgcn_mfma_f32_16x16x32_bf16(bfr[nt], qf[ks], sacc[nt], 0, 0, 0);
    }

    // ---- (4) clip + mask + pack PV A-frag IN REGISTERS; lS b64 for repack ----
    s16x8 pa;
    #pragma unroll
    for (int nt = 0; nt < 2; ++nt) {
      #pragma unroll
      for (int j = 0; j < 4; ++j) {
        float val = fminf(fmaxf(sacc[nt][j], 0.f), 15.f);
        if (!((mword >> (16 * nt + 4 * lhi + j)) & 1u)) val = 0.f;
        pa[nt * 4 + j] = (short)f2bf(val);
      }
      s16x4 h4 = { pa[nt*4], pa[nt*4+1], pa[nt*4+2], pa[nt*4+3] };
      *(s16x4*)(lS + llo * 72 + nt * 32 + lhi * 8) = h4;   // row q=llo, kv*2 offset
    }

    // ---- (5) PV: O[16 x 128] += S @ V^T; A straight from registers ----
    #pragma unroll
    for (int nt = 0; nt < 8; ++nt) {
      s16x8 vb = *(s16x8*)(lVc + nt * 1024 + lane * 16);
      oacc[nt] = __builtin_amdgcn_mfma_f32_16x16x32_bf16(pa, vb, oacc[nt], 0, 0, 0);
    }

    // ---- (6) attn repack: b64 row reads -> f32 full-line stores ----
    #pragma unroll
    for (int p = 0; p < 2; ++p) {
      int rq   = lane >> 3;                 // 0..7
      int part = lane & 7;                  // 0..7 -> kv 4*part..+3
      int r    = 8 * p + rq;                // row within wave's 16
      s16x4 sv = *(s16x4*)(lS + r * 72 + part * 8);
      f32x4 a;
      a[0]=bf2f((uint16_t)sv[0]); a[1]=bf2f((uint16_t)sv[1]);
      a[2]=bf2f((uint16_t)sv[2]); a[3]=bf2f((uint16_t)sv[3]);
      __builtin_nontemporal_store(a,
          (f32x4*)(ag + (size_t)(16 * wq + r) * S_ + kt * BN + part * 4));
    }

    // ---- (7) barrier: DMA (4 ops) done; 2 attn stores stay in flight ----
    asm volatile("s_waitcnt vmcnt(2) lgkmcnt(0)" ::: "memory");
    __builtin_amdgcn_s_barrier();
    __builtin_amdgcn_sched_barrier(0);
    cur ^= 1;
  }

  // ---- epilogue: O store ----
  #pragma unroll
  for (int nt = 0; nt < 8; ++nt) {
    int n = 16 * nt + llo;
    #pragma unroll
    for (int j = 0; j < 4; ++j) {
      int m = 16 * wq + 4 * lhi + j;
      __builtin_nontemporal_store(oacc[nt][j], og + (size_t)m * D_ + n);
    }
  }
}

// ===================== fallback (r5 kernel, passing) ======================
#define LDS_BARRIER() do {                                   \
    asm volatile("s_waitcnt lgkmcnt(0)" ::: "memory");       \
    __builtin_amdgcn_s_barrier();                            \
    __builtin_amdgcn_sched_barrier(0);                       \
  } while (0)

__global__ __launch_bounds__(NTHREADS)
__attribute__((amdgpu_waves_per_eu(4, 4)))
void attn_relu15_fallback(const float* __restrict__ q, const float* __restrict__ k,
                          const float* __restrict__ v, const int* __restrict__ mask,
                          float* __restrict__ outp, float* __restrict__ attnp)
{
  const int blk = blockIdx.x;
  const int g   = (blk & 7) * 128 + (blk >> 3);
  const int bh  = g >> 4;
  const int qt  = g & 15;
  const int b   = bh >> 4;
  const int tid  = threadIdx.x;
  const int lane = tid & 63;
  const int wq   = tid >> 6;
  const int lhi  = lane >> 4;
  const int llo  = lane & 15;

  __shared__ __align__(16) char smem[36864];
  char* const lK0 = smem;
  char* const lV0 = smem + 16384;
  char* const lS  = smem + 32768 + wq * 1024;

  const float* qg = q + (size_t)bh * (S_ * D_) + (size_t)qt * 64 * D_;
  const float* kg = k + (size_t)bh * (S_ * D_);
  const float* vg = v + (size_t)bh * (S_ * D_);
  const int*   mg = mask  + (size_t)b * S_ * S_ + (size_t)qt * 64 * S_;
  float*       ag = attnp + (size_t)bh * S_ * S_ + (size_t)qt * 64 * S_;
  float*       og = outp  + (size_t)bh * (S_ * D_) + (size_t)qt * 64 * D_;
  const float invT = 0.08838834764831843f;

  #define K_O(rep)   ((tid + NTHREADS * (rep)) * 8)
  #define K_ROW(o)   ((((o) >> 10) & 1) * 16 + (((o) >> 4) & 15))
  #define K_COL(o)   (((o) >> 11) * 32 + (((o) >> 8) & 3) * 8 + (((o) >> 3) & 1) * 4)

  s16x8 qf[4];
  {
    const float* qrow = qg + (size_t)(16 * wq + llo) * D_;
    #pragma unroll
    for (int ks = 0; ks < 4; ++ks) {
      int d0 = 32 * ks + 8 * lhi;
      f32x4 x0 = *(const f32x4*)(qrow + d0);
      f32x4 x1 = *(const f32x4*)(qrow + d0 + 4);
      s16x8 h;
      h[0]=f2bf(x0[0]*invT); h[1]=f2bf(x0[1]*invT); h[2]=f2bf(x0[2]*invT); h[3]=f2bf(x0[3]*invT);
      h[4]=f2bf(x1[0]*invT); h[5]=f2bf(x1[1]*invT); h[6]=f2bf(x1[2]*invT); h[7]=f2bf(x1[3]*invT);
      qf[ks] = h;
    }
  }
  {
    #pragma unroll
    for (int rep = 0; rep < 4; ++rep) {
      int o = K_O(rep);
      f32x4 x = *(const f32x4*)(kg + K_ROW(o) * D_ + K_COL(o));
      s16x4 h; h[0]=f2bf(x[0]); h[1]=f2bf(x[1]); h[2]=f2bf(x[2]); h[3]=f2bf(x[3]);
      *(s16x4*)(lK0 + o) = h;
    }
    #pragma unroll
    for (int rep = 0; rep < 4; ++rep) {
      int bid = (tid >> 2) + 64 * rep;
      int kb = bid >> 5, db = bid & 31, l2 = lane & 3;
      f32x4 x = *(const f32x4*)(vg + (size_t)(kb * 4 + l2) * D_ + db * 4);
      float v0=x[0], v1=x[1], v2=x[2], v3=x[3], t;
      t=(l2&1)?v0:v1; t=__shfl_xor(t,1); if(l2&1)v0=t; else v1=t;
      t=(l2&1)?v2:v3; t=__shfl_xor(t,1); if(l2&1)v2=t; else v3=t;
      t=(l2&2)?v0:v2; t=__shfl_xor(t,2); if(l2&2)v0=t; else v2=t;
      t=(l2&2)?v1:v3; t=__shfl_xor(t,2); if(l2&2)v1=t; else v3=t;
      int dd = db * 4 + l2;
      s16x4 h; h[0]=f2bf(v0); h[1]=f2bf(v1); h[2]=f2bf(v2); h[3]=f2bf(v3);
      *(s16x4*)(lV0 + (dd >> 4) * 1024 + ((kb >> 1) & 3) * 256
                    + (dd & 15) * 16 + (kb & 1) * 8) = h;
    }
  }
  LDS_BARRIER();

  f32x4 oacc[8];
  #pragma unroll
  for (int i = 0; i < 8; ++i) oacc[i] = (f32x4){0.f,0.f,0.f,0.f};

  int cur = 0;
  for (int kt = 0; kt < NKT; ++kt) {
    const bool pf = (kt + 1 < NKT);
    char* lKc = lK0 + cur * 8192;
    char* lVc = lV0 + cur * 8192;
    f32x4 kst[4];
    const float* kgt = kg + (size_t)(kt + 1) * BN * D_;
    if (pf) {
      #pragma unroll
      for (int rep = 0; rep < 4; ++rep) {
        int o = K_O(rep);
        kst[rep] = *(const f32x4*)(kgt + K_ROW(o) * D_ + K_COL(o));
      }
    }
    int mreg[8];
    #pragma unroll
    for (int nt = 0; nt < 2; ++nt)
      #pragma unroll
      for (int j = 0; j < 4; ++j)
        mreg[nt * 4 + j] =
          mg[(size_t)(16 * wq + 4 * lhi + j) * S_ + kt * BN + 16 * nt + llo];

    f32x4 sacc[2];
    sacc[0] = (f32x4){0.f,0.f,0.f,0.f}; sacc[1] = sacc[0];
    #pragma unroll
    for (int ks = 0; ks < 4; ++ks) {
      s16x8 bfr[2];
      #pragma unroll
      for (int nt = 0; nt < 2; ++nt)
        bfr[nt] = *(s16x8*)(lKc + (ks * 2 + nt) * 1024 + lane * 16);
      #pragma unroll
      for (int nt = 0; nt < 2; ++nt)
        sacc[nt] = __builtin_amdgcn_mfma_f32_16x16x32_bf16(qf[ks], bfr[nt], sacc[nt], 0, 0, 0);
    }

    f32x4 vst[4];
    const float* vgt = vg + (size_t)(kt + 1) * BN * D_;
    if (pf) {
      char* lKn = lK0 + (cur ^ 1) * 8192;
      #pragma unroll
      for (int rep = 0; rep < 4; ++rep) {
        f32x4 x = kst[rep];
        s16x4 h; h[0]=f2bf(x[0]); h[1]=f2bf(x[1]); h[2]=f2bf(x[2]); h[3]=f2bf(x[3]);
        *(s16x4*)(lKn + K_O(rep)) = h;
      }
      #pragma unroll
      for (int rep = 0; rep < 4; ++rep) {
        int bid = (tid >> 2) + 64 * rep;
        int kb = bid >> 5, db = bid & 31, l2 = lane & 3;
        vst[rep] = *(const f32x4*)(vgt + (size_t)(kb * 4 + l2) * D_ + db * 4);
      }
    }

    #pragma unroll
    for (int nt = 0; nt < 2; ++nt) {
      char* sb = lS + (2 * nt + (llo >> 3)) * 256 + (llo & 7) * 2;
      #pragma unroll
      for (int j = 0; j < 4; ++j) {
        float val = fminf(fmaxf(sacc[nt][j], 0.f), 15.f);
        if (mreg[nt * 4 + j] == 0) val = 0.f;
        *(uint16_t*)(sb + (4 * lhi + j) * 16) = f2bf(val);
      }
    }
    {
      s16x8 saf = *(s16x8*)(lS + lane * 16);
      #pragma unroll
      for (int nt = 0; nt < 8; ++nt) {
        s16x8 vb = *(s16x8*)(lVc + nt * 1024 + lane * 16);
        oacc[nt] = __builtin_amdgcn_mfma_f32_16x16x32_bf16(saf, vb, oacc[nt], 0, 0, 0);
      }
    }
    #pragma unroll
    for (int p = 0; p < 2; ++p) {
      int r  = 16 * wq + p * 8 + (lane >> 3);
      int cb = lane & 7;
      s16x4 sv = *(s16x4*)(lS + (cb >> 1) * 256 + ((r & 15) * 16) + (cb & 1) * 8);
      f32x4 a;
      a[0]=bf2f((uint16_t)sv[0]); a[1]=bf2f((uint16_t)sv[1]);
      a[2]=bf2f((uint16_t)sv[2]); a[3]=bf2f((uint16_t)sv[3]);
      __builtin_nontemporal_store(a, (f32x4*)(ag + (size_t)r * S_ + kt * BN + cb * 4));
    }
    if (pf) {
      char* lVn = lV0 + (cur ^ 1) * 8192;
      #pragma unroll
      for (int rep = 0; rep < 4; ++rep) {
        int bid = (tid >> 2) + 64 * rep;
        int kb = bid >> 5, db = bid & 31, l2 = lane & 3;
        f32x4 x = vst[rep];
        float v0=x[0], v1=x[1], v2=x[2], v3=x[3], t;
        t=(l2&1)?v0:v1; t=__shfl_xor(t,1); if(l2&1)v0=t; else v1=t;
        t=(l2&1)?v2:v3; t=__shfl_xor(t,1); if(l2&1)v2=t; else v3=t;
        t=(l2&2)?v0:v2; t=__shfl_xor(t,2); if(l2&2)v0=t; else v2=t;
        t=(l2&2)?v1:v3; t=__shfl_xor(t,2); if(l2&2)v1=t; else v3=t;
        int dd = db * 4 + l2;
        s16x4 h; h[0]=f2bf(v0); h[1]=f2bf(v1); h[2]=f2bf(v2); h[3]=f2bf(v3);
        *(s16x4*)(lVn + (dd >> 4) * 1024 + ((kb >> 1) & 3) * 256
                      + (dd & 15) * 16 + (kb & 1) * 8) = h;
      }
    }
    LDS_BARRIER();
    cur ^= 1;
  }
  #pragma unroll
  for (int nt = 0; nt < 8; ++nt) {
    int n = 16 * nt + llo;
    #pragma unroll
    for (int j = 0; j < 4; ++j) {
      int m = 16 * wq + 4 * lhi + j;
      __builtin_nontemporal_store(oacc[nt][j], og + (size_t)m * D_ + n);
    }
  }
}

extern "C" void kernel_launch(void* const* d_in, const int* in_sizes, int n_in,
                              void* d_out, int out_size, void* d_ws, size_t ws_size,
                              hipStream_t stream) {
  const float* q    = (const float*)d_in[0];
  const float* k    = (const float*)d_in[1];
  const float* v    = (const float*)d_in[2];
  const int*   mask = (const int*)d_in[3];
  float* outp  = (float*)d_out;
  float* attnp = outp + (size_t)B_ * H_ * S_ * D_;   // tuple: (out, attn) concat

  if (ws_size >= (size_t)WS_NEED && d_ws != nullptr) {
    char*     wsK = (char*)d_ws;
    char*     wsV = wsK + WSK_BYTES;
    uint32_t* wsM = (uint32_t*)(wsK + WSK_BYTES + WSV_BYTES);
    prepass_kernel<<<8704, 256, 0, stream>>>(k, v, mask, wsK, wsV, wsM);
    attn_relu15_main<<<dim3(B_ * H_ * (S_ / BM)), NTHREADS, 0, stream>>>(
        q, wsK, wsV, wsM, outp, attnp);
  } else {
    attn_relu15_fallback<<<dim3(B_ * H_ * (S_ / 64)), NTHREADS, 0, stream>>>(
        q, k, v, mask, outp, attnp);
  }
}